// Round 4
// baseline (2875.874 us; speedup 1.0000x reference)
//
#include <hip/hip_runtime.h>
#include <stdint.h>

typedef unsigned short u16;
typedef unsigned char u8;
typedef unsigned long long u64;
typedef short s16x8 __attribute__((ext_vector_type(8)));
typedef float f32x4 __attribute__((ext_vector_type(4)));
typedef float f32x2 __attribute__((ext_vector_type(2)));
typedef unsigned int u32x4 __attribute__((ext_vector_type(4)));
typedef unsigned int u32x2 __attribute__((ext_vector_type(2)));

#define NB 128
#define NT 512
#define NH 256
#define GQ 8      // batch groups
#define MBQ 16    // batch rows per group
#define STEPS 511

// ---- workspace layout (bytes) ----
#define WS_HBUF 0        // double-buffered h: 2 * GQ * MBQ * 256 * 2B = 131072
#define WS_X12  131072   // 12*64 floats = 3072
#define WS_BAR  134144   // 8 groups * 4 flags * 128B = 4096

// ---- dynamic LDS layout (bytes) ----
#define OFF_H     0        // h tile:   16 rows * 264 u16 = 8448
#define OFF_PRE   8448     // pre:      7 gates * 16 * 72 u16 = 16128
#define OFF_G     24576    // gates:    7 * 16 * 68 f32 = 30464
#define OFF_XC    55040    // xc table: 7 * 64 * 13 f32 = 23296
#define OFF_B2    78336    // g_b2 slice: 7*64 f32 = 1792
#define OFF_IW    80128    // i_W slice: 64 f32 = 256
#define OFF_X12   80384    // x12: 12*64 f32 = 3072
#define OFF_IDXA  83456    // idx_all: 511*16 u8 -> 8192
#define OFF_DTA   91648    // dt_all: 511*16 f32 = 32704
#define SMEM_BYTES 124416

__device__ __forceinline__ u16 f2bf(float f) {
  unsigned u = __float_as_uint(f);
  u += 0x7FFFu + ((u >> 16) & 1u);  // round-to-nearest-even
  return (u16)(u >> 16);
}
__device__ __forceinline__ float sigm(float x) { return 1.0f / (1.0f + __expf(-x)); }
__device__ __forceinline__ float tanh_fast(float x) {
  float e = __expf(2.0f * x);
  return 1.0f - 2.0f / (e + 1.0f);   // NaN-free: x->+inf => 1, x->-inf => -1
}
__device__ __forceinline__ float softplus_f(float x) {
  return fmaxf(x, 0.0f) + __logf(1.0f + __expf(-fabsf(x)));
}

// ---------------- prep: 12 embeddings, zero h buf0, reset barrier flags ----------------
__global__ void ct4_prep(const float* __restrict__ etW1, const float* __restrict__ etb1,
                         const float* __restrict__ etW2, const float* __restrict__ etb2,
                         const float* __restrict__ esW1, const float* __restrict__ esb1,
                         const float* __restrict__ esW2, const float* __restrict__ esb2,
                         char* __restrict__ ws) {
  __shared__ float sT[4][64];
  __shared__ float sS[3][64];
  const int i = threadIdx.x;  // 64 threads
  #pragma unroll
  for (int e = 0; e < 4; ++e) sT[e][i] = tanhf(etW1[i * 4 + e] + etb1[i]);
  #pragma unroll
  for (int s = 0; s < 3; ++s) sS[s][i] = tanhf(esW1[i * 3 + s] + esb1[i]);
  __syncthreads();
  float te[4], se[3];
  #pragma unroll
  for (int e = 0; e < 4; ++e) {
    float a = etb2[i];
    for (int jj = 0; jj < 64; ++jj) a += sT[e][jj] * etW2[i * 64 + jj];
    te[e] = tanhf(a);
  }
  #pragma unroll
  for (int s = 0; s < 3; ++s) {
    float a = esb2[i];
    for (int jj = 0; jj < 64; ++jj) a += sS[s][jj] * esW2[i * 64 + jj];
    se[s] = tanhf(a);
  }
  float* x12 = (float*)(ws + WS_X12);
  #pragma unroll
  for (int e = 0; e < 4; ++e)
    #pragma unroll
    for (int s = 0; s < 3; ++s) x12[(e * 3 + s) * 64 + i] = te[e] + se[s];
  // zero h buffer 0 (first 65536 bytes of WS_HBUF)
  u32x4* hz = (u32x4*)(ws + WS_HBUF);
  u32x4 z = {0u, 0u, 0u, 0u};
  for (int p = i; p < 65536 / 16; p += 64) hz[p] = z;
  // reset barrier flags
  int* bars = (int*)(ws + WS_BAR);
  for (int p = i; p < 1024; p += 64) bars[p] = 0;
}

// ---------------- main persistent recurrence kernel ----------------
// grid: 32 blocks x 256 threads (4 waves, 1 wave/SIMD at 1 block/CU -> 512 unified regs/wave).
// block (grp = bid&7, j = bid>>3): batch rows [grp*16, grp*16+16), hidden block j (64 units).
// Wave w owns gates {2w, 2w+1} (wave 3: gate 6 only + remote-h pull duty).
// Exchange: device-scope relaxed atomics (sc1) for h stores -> syncthreads (vmcnt drain) ->
// relaxed flag store; wave 3 polls remote flags and pulls 3x2KB remote h into LDS while
// other waves pre-accumulate the LOCAL K-tiles of GEMM1 and issue output stores.
__global__ __launch_bounds__(256, 1) void ct4_main(
    const int* __restrict__ ev, const float* __restrict__ ts, const int* __restrict__ mk,
    const float* __restrict__ gW1, const float* __restrict__ gb1,
    const float* __restrict__ gW2, const float* __restrict__ gb2,
    const float* __restrict__ iW, const float* __restrict__ ibp,
    float* __restrict__ out, char* __restrict__ ws) {
  extern __shared__ char smem[];
  u16* h_lds = (u16*)(smem + OFF_H);          // [16][264]
  float* g_lds = (float*)(smem + OFF_G);      // [7][16][68]
  float* xc_lds = (float*)(smem + OFF_XC);    // [(k*64+o)*13 + m]
  float* b2_lds = (float*)(smem + OFF_B2);    // [7][64]
  float* iw_lds = (float*)(smem + OFF_IW);    // [64]
  float* x12_lds = (float*)(smem + OFF_X12);  // [12][64]
  u8* idx_all = (u8*)(smem + OFF_IDXA);       // [511*16]
  float* dt_all = (float*)(smem + OFF_DTA);   // [511*16]

  const int tid = threadIdx.x;
  const int bid = blockIdx.x;
  const int grp = bid & 7;
  const int j = bid >> 3;
  const int b0 = grp * MBQ;
  const int wave = tid >> 6;     // 0..3
  const int q = (tid >> 4) & 3;
  const int c = tid & 15;
  const int kloc0 = 2 * j;       // local K tiles (32-wide) are {2j, 2j+1}

  u16* hbuf = (u16*)(ws + WS_HBUF);
  int* bars = (int*)(ws + WS_BAR);
  int* myflag = bars + grp * 128 + j * 32;

  // ---- prologue ----
  for (int p = tid; p < 12 * 64; p += 256) x12_lds[p] = ((const float*)(ws + WS_X12))[p];
  for (int p = tid; p < 16 * 264 / 2; p += 256) ((unsigned*)h_lds)[p] = 0u;  // h(0)=0
  for (int p = tid; p < 448; p += 256) {
    int kk = p >> 6, o = p & 63;
    b2_lds[kk * 64 + o] = gb2[kk * 256 + j * 64 + o];
  }
  if (tid < 64) iw_lds[tid] = iW[j * 256 + j * 64 + tid];
  const float ibj = ibp[j];
  // preload all per-step indices / dts into LDS
  for (int p = tid; p < STEPS * 16; p += 256) {
    int t = p >> 4, b = p & 15;
    idx_all[p] = (u8)(ev[(b0 + b) * NT + t] * 3 + mk[(b0 + b) * NT + t]);
    dt_all[p] = ts[(b0 + b) * NT + t + 1];
  }
  __syncthreads();
  // xc table: xc[k][o][m] = g_b1[k][j*64+o] + sum_i x12[m][i] * W1[k][j*64+o][i]
  for (int r = tid; r < 448; r += 256) {
    int kk = r >> 6, o = r & 63;
    const float* row = gW1 + (size_t)(kk * 256 + j * 64 + o) * 320;
    float a[12];
    float bb = gb1[kk * 256 + j * 64 + o];
    #pragma unroll
    for (int m = 0; m < 12; ++m) a[m] = bb;
    for (int i = 0; i < 64; ++i) {
      float w = row[i];
      #pragma unroll
      for (int m = 0; m < 12; ++m) a[m] += x12_lds[m * 64 + i] * w;
    }
    #pragma unroll
    for (int m = 0; m < 12; ++m) xc_lds[(kk * 64 + o) * 13 + m] = a[m];
  }

  // weight fragments (register-resident, bf16). Slot order: s=0..5 remote K tiles
  // (kt = s + (s >= 2j ? 2 : 0)), s=6..7 local K tiles (kt = 2j, 2j+1).
  s16x8 a1[2][4][8];  // [gate-in-wave][mt][kslot] : 256 regs
  s16x8 a2[2][4][2];  // [gate-in-wave][mt][kt]    : 64 regs
  #pragma unroll
  for (int gg = 0; gg < 2; ++gg) {
    const int k = 2 * wave + gg;
    if (k < 7) {
      #pragma unroll
      for (int s = 0; s < 8; ++s) {
        int kt = (s < 6) ? (s + (s >= kloc0 ? 2 : 0)) : (kloc0 + (s - 6));
        #pragma unroll
        for (int mt = 0; mt < 4; ++mt) {
          const float* p = gW1 + (size_t)(k * 256 + j * 64 + 16 * mt + c) * 320 + 64 + 32 * kt + 8 * q;
          union { s16x8 v; u16 u[8]; } fr;
          #pragma unroll
          for (int i = 0; i < 8; ++i) fr.u[i] = f2bf(p[i]);
          a1[gg][mt][s] = fr.v;
        }
      }
      #pragma unroll
      for (int mt = 0; mt < 4; ++mt)
        #pragma unroll
        for (int kt = 0; kt < 2; ++kt) {
          const float* p = gW2 + (size_t)(k * 256 + j * 64 + 16 * mt + c) * 256 + j * 64 + 32 * kt + 8 * q;
          union { s16x8 v; u16 u[8]; } fr;
          #pragma unroll
          for (int i = 0; i < 8; ++i) fr.u[i] = f2bf(p[i]);
          a2[gg][mt][kt] = fr.v;
        }
    }
  }

  float ccA[4] = {0.f, 0.f, 0.f, 0.f};   // c state (4 elems per thread)
  float cctA[4] = {0.f, 0.f, 0.f, 0.f};  // c_target state
  f32x4 acc[2][4] = {};                  // GEMM1 accumulators (local tiles pre-accumulated)
  const f32x4 fzero = {};
  __syncthreads();

  const int O_CELL = NB * STEPS * 4;
  const int SZB = NB * STEPS * NH;
  const int O_CT = O_CELL + SZB;
  const int O_OUT = O_CT + SZB;
  const int O_DEC = O_OUT + SZB;

  for (int t = 0; t < STEPS; ++t) {
    // ---- top: GEMM1 remote tiles, tanh, GEMM2 (per owned gate) ----
    {
      s16x8 bfr[6];
      #pragma unroll
      for (int s = 0; s < 6; ++s) {
        int ks = s + (s >= kloc0 ? 2 : 0);
        bfr[s] = *(const s16x8*)&h_lds[c * 264 + 32 * ks + 8 * q];
      }
      int midx = (int)idx_all[t * 16 + c];
      #pragma unroll
      for (int gg = 0; gg < 2; ++gg) {
        const int k = 2 * wave + gg;
        if (k < 7) {
          #pragma unroll
          for (int s = 0; s < 6; ++s)
            #pragma unroll
            for (int mt = 0; mt < 4; ++mt)
              acc[gg][mt] = __builtin_amdgcn_mfma_f32_16x16x32_bf16(a1[gg][mt][s], bfr[s], acc[gg][mt], 0, 0, 0);
          u16* preW = (u16*)(smem + OFF_PRE) + k * (16 * 72);
          #pragma unroll
          for (int mt = 0; mt < 4; ++mt) {
            int o = 16 * mt + 4 * q;
            const float* xr = &xc_lds[(k * 64 + o) * 13 + midx];
            u16 u0 = f2bf(tanh_fast(acc[gg][mt][0] + xr[0]));
            u16 u1 = f2bf(tanh_fast(acc[gg][mt][1] + xr[13]));
            u16 u2 = f2bf(tanh_fast(acc[gg][mt][2] + xr[26]));
            u16 u3 = f2bf(tanh_fast(acc[gg][mt][3] + xr[39]));
            u32x2 pk;
            pk[0] = (unsigned)u0 | ((unsigned)u1 << 16);
            pk[1] = (unsigned)u2 | ((unsigned)u3 << 16);
            *(u32x2*)&preW[c * 72 + o] = pk;  // pre[b=c][o..o+3], bf16
          }
          f32x4 acc2[4] = {};
          #pragma unroll
          for (int kt = 0; kt < 2; ++kt) {
            s16x8 pf = *(const s16x8*)&preW[c * 72 + 32 * kt + 8 * q];
            #pragma unroll
            for (int mt = 0; mt < 4; ++mt)
              acc2[mt] = __builtin_amdgcn_mfma_f32_16x16x32_bf16(a2[gg][mt][kt], pf, acc2[mt], 0, 0, 0);
          }
          #pragma unroll
          for (int mt = 0; mt < 4; ++mt)
            *(f32x4*)&g_lds[(k * 16 + c) * 68 + 16 * mt + 4 * q] = acc2[mt];
        }
      }
    }
    __syncthreads();

    // ---- phase C: gates, cell update, h_new (256 threads x 4 elems) ----
    const int b = tid >> 4, o4 = (tid & 15) * 4;
    float ip = 0.f;
    float ci[4], ctn[4], opv[4], dcv[4];
    {
      float dtv = dt_all[t * 16 + b];
      float G[7][4];
      #pragma unroll
      for (int kk = 0; kk < 7; ++kk) {
        f32x4 gg4 = *(const f32x4*)&g_lds[(kk * 16 + b) * 68 + o4];
        #pragma unroll
        for (int e = 0; e < 4; ++e) G[kk][e] = gg4[e] + b2_lds[kk * 64 + o4 + e];
      }
      float hnv[4];
      #pragma unroll
      for (int e = 0; e < 4; ++e) {
        float inp = sigm(G[0][e]);
        float fg = sigm(G[1][e]);
        float op = sigm(G[2][e]);
        float itg = sigm(G[3][e]);
        float ftg = sigm(G[4][e]);
        float z = tanh_fast(G[5][e]);
        float dc = softplus_f(G[6][e]);
        float c_i = fg * ccA[e] + inp * z;
        float c_t = ftg * cctA[e] + itg * z;
        float edv = __expf(-dc * dtv);
        float c_n = c_t + (c_i - c_t) * edv;
        float h_n = op * tanh_fast(c_n);
        ccA[e] = c_n;
        cctA[e] = c_t;
        ci[e] = c_i; ctn[e] = c_t; opv[e] = op; dcv[e] = dc;
        hnv[e] = h_n;
        ip += iw_lds[o4 + e] * h_n;
      }
      if (t < STEPS - 1) {
        u64 hp = (u64)f2bf(hnv[0]) | ((u64)f2bf(hnv[1]) << 16) |
                 ((u64)f2bf(hnv[2]) << 32) | ((u64)f2bf(hnv[3]) << 48);
        *(u64*)&h_lds[b * 264 + j * 64 + o4] = hp;  // local columns of h(t+1)
        __hip_atomic_store((u64*)&hbuf[((size_t)(((t + 1) & 1) * GQ + grp) * MBQ + b) * 256 + j * 64 + o4],
                           hp, __ATOMIC_RELAXED, __HIP_MEMORY_SCOPE_AGENT);
      }
    }
    __syncthreads();  // drains h stores (vmcnt 0) + orders h_lds local writes

    // C2: output stores + intensity (issued under the exchange latency)
    auto C2 = [&]() {
      size_t base = ((size_t)(b0 + b) * STEPS + t) * NH + j * 64 + o4;
      f32x4 v;
      #pragma unroll
      for (int e = 0; e < 4; ++e) v[e] = ci[e];
      __builtin_nontemporal_store(v, (f32x4*)&out[O_CELL + base]);
      #pragma unroll
      for (int e = 0; e < 4; ++e) v[e] = ctn[e];
      __builtin_nontemporal_store(v, (f32x4*)&out[O_CT + base]);
      #pragma unroll
      for (int e = 0; e < 4; ++e) v[e] = opv[e];
      __builtin_nontemporal_store(v, (f32x4*)&out[O_OUT + base]);
      #pragma unroll
      for (int e = 0; e < 4; ++e) v[e] = dcv[e];
      __builtin_nontemporal_store(v, (f32x4*)&out[O_DEC + base]);
      #pragma unroll
      for (int d = 1; d < 16; d <<= 1) ip += __shfl_xor(ip, d, 16);
      if ((tid & 15) == 0)
        __builtin_nontemporal_store(softplus_f(ip + ibj),
                                    &out[((size_t)(b0 + b) * STEPS + t) * 4 + j]);
    };

    if (t < STEPS - 1) {
      if (tid == 0) __hip_atomic_store(myflag, t + 1, __ATOMIC_RELAXED, __HIP_MEMORY_SCOPE_AGENT);
      // GEMM1 local tiles of h(t+1) (available in LDS now) while remote h is in flight
      {
        s16x8 bfl[2];
        #pragma unroll
        for (int sl = 0; sl < 2; ++sl)
          bfl[sl] = *(const s16x8*)&h_lds[c * 264 + 32 * (kloc0 + sl) + 8 * q];
        #pragma unroll
        for (int gg = 0; gg < 2; ++gg) {
          const int k = 2 * wave + gg;
          if (k < 7) {
            #pragma unroll
            for (int mt = 0; mt < 4; ++mt) acc[gg][mt] = fzero;
            #pragma unroll
            for (int sl = 0; sl < 2; ++sl)
              #pragma unroll
              for (int mt = 0; mt < 4; ++mt)
                acc[gg][mt] = __builtin_amdgcn_mfma_f32_16x16x32_bf16(a1[gg][mt][6 + sl], bfl[sl], acc[gg][mt], 0, 0, 0);
          }
        }
      }
      C2();
      if (wave == 3) {
        // wave 3: poll remote flags, pull 3x2KB of remote h(t+1)
        const int l = tid & 63;
        const int row = l >> 2;
        const int segb = (l & 3) * 32;  // byte offset within the 128B row-chunk
        int* f0p = bars + grp * 128 + (0 + (0 >= j)) * 32;
        int* f1p = bars + grp * 128 + (1 + (1 >= j)) * 32;
        int* f2p = bars + grp * 128 + (2 + (2 >= j)) * 32;
        for (;;) {
          int f0 = __hip_atomic_load(f0p, __ATOMIC_RELAXED, __HIP_MEMORY_SCOPE_AGENT);
          int f1 = __hip_atomic_load(f1p, __ATOMIC_RELAXED, __HIP_MEMORY_SCOPE_AGENT);
          int f2 = __hip_atomic_load(f2p, __ATOMIC_RELAXED, __HIP_MEMORY_SCOPE_AGENT);
          if (f0 > t && f1 > t && f2 > t) break;
          __builtin_amdgcn_s_sleep(1);
        }
        const char* rbase = (const char*)hbuf +
            ((size_t)(((t + 1) & 1) * GQ + grp) * MBQ + row) * 512 + segb;
        u64 dv[3][4];
        #pragma unroll
        for (int rb = 0; rb < 3; ++rb) {
          int jr = rb + (rb >= j);
          const u64* src = (const u64*)(rbase + jr * 128);
          #pragma unroll
          for (int kq = 0; kq < 4; ++kq)
            dv[rb][kq] = __hip_atomic_load(src + kq, __ATOMIC_RELAXED, __HIP_MEMORY_SCOPE_AGENT);
        }
        char* lbase = (char*)h_lds + row * 528 + segb;
        #pragma unroll
        for (int rb = 0; rb < 3; ++rb) {
          int jr = rb + (rb >= j);
          #pragma unroll
          for (int kq = 0; kq < 4; ++kq)
            *(u64*)(lbase + jr * 128 + 8 * kq) = dv[rb][kq];
        }
      }
      __syncthreads();  // remote h_lds writes visible to all waves
    } else {
      C2();
    }
  }
}

extern "C" void kernel_launch(void* const* d_in, const int* in_sizes, int n_in,
                              void* d_out, int out_size, void* d_ws, size_t ws_size,
                              hipStream_t stream) {
  const int* ev = (const int*)d_in[0];
  const float* ts = (const float*)d_in[1];
  const int* mk = (const int*)d_in[2];
  const float* etW1 = (const float*)d_in[3];
  const float* etb1 = (const float*)d_in[4];
  const float* etW2 = (const float*)d_in[5];
  const float* etb2 = (const float*)d_in[6];
  const float* esW1 = (const float*)d_in[7];
  const float* esb1 = (const float*)d_in[8];
  const float* esW2 = (const float*)d_in[9];
  const float* esb2 = (const float*)d_in[10];
  const float* gW1 = (const float*)d_in[11];
  const float* gb1 = (const float*)d_in[12];
  const float* gW2 = (const float*)d_in[13];
  const float* gb2 = (const float*)d_in[14];
  const float* iW = (const float*)d_in[15];
  const float* ibv = (const float*)d_in[16];
  char* ws = (char*)d_ws;
  float* out = (float*)d_out;

  ct4_prep<<<1, 64, 0, stream>>>(etW1, etb1, etW2, etb2, esW1, esb1, esW2, esb2, ws);
  (void)hipFuncSetAttribute((const void*)ct4_main,
                            hipFuncAttributeMaxDynamicSharedMemorySize, SMEM_BYTES);
  ct4_main<<<GQ * 4, 256, SMEM_BYTES, stream>>>(ev, ts, mk, gW1, gb1, gW2, gb2, iW, ibv, out, ws);
}